// Round 6
// baseline (124.211 us; speedup 1.0000x reference)
//
#include <hip/hip_runtime.h>
#include <hip/hip_fp16.h>
#include <math.h>

// N=20000, K=16, in_dim=128, out_dim=128, H1=H2=16
// Hermitian-reduced spectrum: e = v*16 + u, v=0..8, u=0..15  -> NE=144
#define IN_DIM 128
#define NE 144
#define OUT_DIM 128
#define KNBR 16

__device__ __forceinline__ float2 cmul(float2 a, float2 b) {
    return make_float2(a.x * b.x - a.y * b.y, a.x * b.y + a.y * b.x);
}

__device__ __forceinline__ float2 cprod8h(const __half2* f) {
    float2 c[8];
#pragma unroll
    for (int k = 0; k < 8; ++k) c[k] = __half22float2(f[k]);
    float2 g0 = cmul(c[0], c[1]);
    float2 g1 = cmul(c[2], c[3]);
    float2 g2 = cmul(c[4], c[5]);
    float2 g3 = cmul(c[6], c[7]);
    return cmul(cmul(g0, g1), cmul(g2, g3));
}

// ---------------------------------------------------------------------------
// Merged prep. Blocks 0..127: W_fft2 row d=blockIdx.x. Block 128: b_fft2.
// Blocks 129..272: W_eff2 row e=blockIdx.x-129.
//   W_fft2[d][e] = sum_rc W_aff[d][rc] * exp(-2*pi*i*(u*r+v*c)/16)
//   W_eff2[e][j] = wt/256 * (Re, -Im) of sum_rc exp(+2*pi*i*(u*r+v*c)/16)
//                  * W_mlp[rc][j],  wt = (v==0||v==8) ? 1 : 2
// ---------------------------------------------------------------------------
__global__ __launch_bounds__(256) void k_prep(
    const float* __restrict__ W_aff, const float* __restrict__ b_aff,
    const float* __restrict__ W_mlp,
    float2* __restrict__ W_fft2, float2* __restrict__ b_fft2,
    float2* __restrict__ W_eff2)
{
    __shared__ float twc[16], tws[16];
    const int t = threadIdx.x;
    if (t < 16) {
        float a = (float)M_PI * (float)t / 8.0f;   // 2*pi*t/16
        twc[t] = cosf(a);
        tws[t] = sinf(a);
    }
    __syncthreads();

    if (blockIdx.x < 129) {
        // ---- forward-DFT fold of W_aff / b_aff
        const int e = t;
        if (e >= NE) return;
        const int u = e & 15, v = e >> 4;
        const float* src = (blockIdx.x == 128) ? b_aff
                                               : (W_aff + blockIdx.x * 256);
        float ar = 0.f, ai = 0.f;
        for (int rc = 0; rc < 256; ++rc) {
            int m = (u * (rc >> 4) + v * (rc & 15)) & 15;
            float x = src[rc];                      // uniform -> s_load
            ar = fmaf(x, twc[m], ar);
            ai = fmaf(x, -tws[m], ai);
        }
        if (blockIdx.x == 128) b_fft2[e] = make_float2(ar, ai);
        else                   W_fft2[blockIdx.x * NE + e] = make_float2(ar, ai);
    } else {
        // ---- inverse-DFT+Re fold of W_mlp (threads 128..255 idle; prep is tiny)
        const int j = t;
        if (j >= 128) return;
        const int e = blockIdx.x - 129;            // 0..143
        const int u = e & 15, v = e >> 4;
        float A = 0.f, B = 0.f;
        for (int rc = 0; rc < 256; ++rc) {
            int m = (u * (rc >> 4) + v * (rc & 15)) & 15;
            float wv_ = W_mlp[rc * 128 + j];        // coalesced
            A = fmaf(wv_, twc[m], A);
            B = fmaf(wv_, tws[m], B);
        }
        const float s = ((v == 0) || (v == 8)) ? (1.0f / 256.0f)
                                               : (2.0f / 256.0f);
        W_eff2[e * 128 + j] = make_float2(A * s, -B * s);
    }
}

// ---------------------------------------------------------------------------
// Kernel 1 v4: spectra GEMM, BM=8 nodes/block for 2x occupancy.
// 192 threads (3 waves), grid N/8=2500 -> ~7.3 waves/SIMD.
// Thread t: e-group g=t>>2 (E=3 elements), m-group mg=t&3 (M=2 nodes).
// Per d: 1 ds_read_b64 + 3 float2 VMEM (shared by 4 lanes) + 12 FMA.
// ---------------------------------------------------------------------------
__global__ __launch_bounds__(192) void k_spectra(
    const float* __restrict__ feat, const float2* __restrict__ W_fft2,
    const float2* __restrict__ b_fft2, __half2* __restrict__ F2h)
{
    __shared__ float featT[IN_DIM * 8];    // featT[d*8 + m], 4 KB
    const int t = threadIdx.x;
    const int node0 = blockIdx.x * 8;

    // stage transposed feature tile: 256 float4 chunks
    for (int i = t; i < 256; i += 192) {
        const int m = i & 7, d4 = i >> 3;
        const float4 v = *(const float4*)&feat[(node0 + m) * IN_DIM + 4 * d4];
        featT[(4 * d4 + 0) * 8 + m] = v.x;
        featT[(4 * d4 + 1) * 8 + m] = v.y;
        featT[(4 * d4 + 2) * 8 + m] = v.z;
        featT[(4 * d4 + 3) * 8 + m] = v.w;
    }
    __syncthreads();

    const int g  = t >> 2;        // e-group 0..47
    const int mg = t & 3;         // m-group 0..3
    const int e0 = g * 3;
    const int m0 = mg * 2;

    float2 acc[3][2];
#pragma unroll
    for (int ei = 0; ei < 3; ++ei)
#pragma unroll
        for (int mi = 0; mi < 2; ++mi) acc[ei][mi] = make_float2(0.f, 0.f);

#pragma unroll 4
    for (int d = 0; d < IN_DIM; ++d) {
        const float2 fv = *(const float2*)&featT[d * 8 + m0];   // 8B LDS
        const float2 w0 = W_fft2[d * NE + e0 + 0];  // 4 lanes share addr
        const float2 w1 = W_fft2[d * NE + e0 + 1];
        const float2 w2 = W_fft2[d * NE + e0 + 2];
        const float f[2] = {fv.x, fv.y};
#pragma unroll
        for (int mi = 0; mi < 2; ++mi) {
            acc[0][mi].x = fmaf(f[mi], w0.x, acc[0][mi].x);
            acc[0][mi].y = fmaf(f[mi], w0.y, acc[0][mi].y);
            acc[1][mi].x = fmaf(f[mi], w1.x, acc[1][mi].x);
            acc[1][mi].y = fmaf(f[mi], w1.y, acc[1][mi].y);
            acc[2][mi].x = fmaf(f[mi], w2.x, acc[2][mi].x);
            acc[2][mi].y = fmaf(f[mi], w2.y, acc[2][mi].y);
        }
    }

#pragma unroll
    for (int ei = 0; ei < 3; ++ei) {
        const float2 b = b_fft2[e0 + ei];
#pragma unroll
        for (int mi = 0; mi < 2; ++mi) {
            F2h[(node0 + m0 + mi) * NE + e0 + ei] =
                __floats2half2_rn(acc[ei][mi].x + b.x, acc[ei][mi].y + b.y);
        }
    }
}

// ---------------------------------------------------------------------------
// Kernel 2 (unchanged from R5): gather + product + folded MLP.
// 8 nodes/block, 256 threads. Wave w owns nodes {2w, 2w+1} for the product
// (lane covers e = lane, lane+64, lane+128<16); P through LDS; MLP phase
// wave w owns e-slice [36w, 36w+36); cross-wave reduce via LDS.
// ---------------------------------------------------------------------------
__global__ __launch_bounds__(256) void k_gather_mlp(
    const int* __restrict__ nbr, const __half2* __restrict__ F2h,
    const float2* __restrict__ W_eff2, const float* __restrict__ b_mlp,
    float* __restrict__ out)
{
    const int node0 = blockIdx.x * 8;
    const int tid  = threadIdx.x;
    const int lane = tid & 63;
    const int w    = __builtin_amdgcn_readfirstlane(tid >> 6);

    __shared__ float2 P_lds[8][NE];       // 9.2 KB
    __shared__ float  part[4][8][128];    // 16 KB

    // ---- product phase
#pragma unroll
    for (int mi = 0; mi < 2; ++mi) {
        const int m = 2 * w + mi;
        const int* nrow = nbr + (node0 + m) * KNBR;

        __half2 fA[8], fB[8], fA2[8], fB2[8];
        const int eA = lane, eB = lane + 64;
#pragma unroll
        for (int k = 0; k < 8; ++k) {
            const __half2* base = F2h + (size_t)nrow[k] * NE;   // s_load idx
            fA[k] = base[eA];
            fB[k] = base[eB];
        }
#pragma unroll
        for (int k = 0; k < 8; ++k) {
            const __half2* base = F2h + (size_t)nrow[k + 8] * NE;
            fA2[k] = base[eA];
            fB2[k] = base[eB];
        }
        P_lds[m][eA] = cmul(cprod8h(fA), cprod8h(fA2));
        P_lds[m][eB] = cmul(cprod8h(fB), cprod8h(fB2));

        if (lane < 16) {
            const int eC = lane + 128;
            __half2 fC[8], fC2[8];
#pragma unroll
            for (int k = 0; k < 8; ++k) {
                fC[k]  = F2h[(size_t)nrow[k] * NE + eC];
                fC2[k] = F2h[(size_t)nrow[k + 8] * NE + eC];
            }
            P_lds[m][eC] = cmul(cprod8h(fC), cprod8h(fC2));
        }
    }
    __syncthreads();

    // ---- MLP phase: wave w handles e in [36w, 36w+36)
    float acc0[8], acc1[8];
#pragma unroll
    for (int m = 0; m < 8; ++m) { acc0[m] = 0.f; acc1[m] = 0.f; }

    const int e0 = w * 36;
#pragma unroll 4
    for (int le = 0; le < 36; ++le) {
        const int e = e0 + le;                        // wave-uniform
        const float2 w0 = W_eff2[e * 128 + lane];
        const float2 w1 = W_eff2[e * 128 + 64 + lane];
#pragma unroll
        for (int m = 0; m < 8; ++m) {
            const float2 p = P_lds[m][e];             // uniform -> broadcast
            acc0[m] = fmaf(p.x, w0.x, fmaf(p.y, w0.y, acc0[m]));
            acc1[m] = fmaf(p.x, w1.x, fmaf(p.y, w1.y, acc1[m]));
        }
    }

#pragma unroll
    for (int m = 0; m < 8; ++m) {
        part[w][m][lane]      = acc0[m];
        part[w][m][lane + 64] = acc1[m];
    }
    __syncthreads();

    // ---- cross-wave reduction: 1024 outputs, 4 per thread
    {
        const int m = tid >> 5;
        const int j = (tid & 31) * 4;
        float4 s = *(const float4*)&b_mlp[j];
#pragma unroll
        for (int w4 = 0; w4 < 4; ++w4) {
            const float4 p = *(const float4*)&part[w4][m][j];
            s.x += p.x; s.y += p.y; s.z += p.z; s.w += p.w;
        }
        *(float4*)&out[(node0 + m) * OUT_DIM + j] = s;
    }
}

extern "C" void kernel_launch(void* const* d_in, const int* in_sizes, int n_in,
                              void* d_out, int out_size, void* d_ws, size_t ws_size,
                              hipStream_t stream) {
    const float* feature   = (const float*)d_in[0];
    const int*   neighbors = (const int*)d_in[1];
    const float* W_aff     = (const float*)d_in[2];
    const float* b_aff     = (const float*)d_in[3];
    const float* W_mlp     = (const float*)d_in[4];
    const float* b_mlp     = (const float*)d_in[5];
    float*       out       = (float*)d_out;

    const int N = in_sizes[0] / IN_DIM;   // 20000

    float2*  W_fft2 = (float2*)d_ws;           // 128*144
    float2*  b_fft2 = W_fft2 + 128 * NE;       // 144
    float2*  W_eff2 = b_fft2 + NE;             // 144*128
    __half2* F2h    = (__half2*)(W_eff2 + NE * 128);  // N*144 * 4B (~11.5 MB)

    k_prep<<<273, 256, 0, stream>>>(W_aff, b_aff, W_mlp, W_fft2, b_fft2, W_eff2);
    k_spectra<<<N / 8, 192, 0, stream>>>(feature, W_fft2, b_fft2, F2h);
    k_gather_mlp<<<N / 8, 256, 0, stream>>>(neighbors, F2h, W_eff2, b_mlp, out);
}

// Round 7
// 86.643 us; speedup vs baseline: 1.4336x; 1.4336x over previous
//
#include <hip/hip_runtime.h>
#include <hip/hip_fp16.h>
#include <math.h>

// N=20000, K=16, in_dim=128, out_dim=128, H1=H2=16
// Hermitian-reduced spectrum: e = v*16 + u, v=0..8, u=0..15  -> NE=144
// Spectra GEMM via MFMA: C[20000 x 288] = feat_h[20000 x 128] @ B[128 x 288]
// where B half-cols are (re,im)-interleaved W_fft2.
#define IN_DIM 128
#define NE 144
#define NCOL 288           // NE*2 half-columns
#define NT 18              // NCOL/16 N-tiles
#define OUT_DIM 128
#define KNBR 16

typedef _Float16 f16x8 __attribute__((ext_vector_type(8)));
typedef float    f32x4 __attribute__((ext_vector_type(4)));

__device__ __forceinline__ float2 cmul(float2 a, float2 b) {
    return make_float2(a.x * b.x - a.y * b.y, a.x * b.y + a.y * b.x);
}

__device__ __forceinline__ float2 cprod8h(const __half2* f) {
    float2 c[8];
#pragma unroll
    for (int k = 0; k < 8; ++k) c[k] = __half22float2(f[k]);
    float2 g0 = cmul(c[0], c[1]);
    float2 g1 = cmul(c[2], c[3]);
    float2 g2 = cmul(c[4], c[5]);
    float2 g3 = cmul(c[6], c[7]);
    return cmul(cmul(g0, g1), cmul(g2, g3));
}

// ---------------------------------------------------------------------------
// feat f32 -> f16, fully coalesced. 2500 blocks x 256 thr x 4 floats.
// ---------------------------------------------------------------------------
__global__ __launch_bounds__(256) void k_feat_half(
    const float* __restrict__ feat, __half2* __restrict__ feat_h2)
{
    const int idx = blockIdx.x * 256 + threadIdx.x;   // 0..639999
    const float4 v = ((const float4*)feat)[idx];
    feat_h2[2 * idx + 0] = __floats2half2_rn(v.x, v.y);
    feat_h2[2 * idx + 1] = __floats2half2_rn(v.z, v.w);
}

// ---------------------------------------------------------------------------
// Merged prep.
// Blocks 0..127 (row d): W_fft2[d][e] = sum_rc W_aff[d][rc]*exp(-i*2pi*(ur+vc)/16)
//   packed straight into MFMA B-fragment order:
//   Bp[((kt*NT + nt)*64 + lane)*8 + i] = B[kt*32 + (lane>>4)*8 + i][nt*16 + (lane&15)]
//   with B[k][c] = (c even) ? Re W_fft2[k][c/2] : Im W_fft2[k][c/2].
// Block 128: bias -> bf[288] f32 row (re,im interleaved).
// Blocks 129..272: W_eff2 row e (folded IFFT2+Re+Hermitian weight x W_mlp).
// ---------------------------------------------------------------------------
__global__ __launch_bounds__(256) void k_prep(
    const float* __restrict__ W_aff, const float* __restrict__ b_aff,
    const float* __restrict__ W_mlp,
    __half* __restrict__ Bp, float* __restrict__ bf,
    float2* __restrict__ W_eff2)
{
    __shared__ float twc[16], tws[16];
    const int t = threadIdx.x;
    if (t < 16) {
        float a = (float)M_PI * (float)t / 8.0f;   // 2*pi*t/16
        twc[t] = cosf(a);
        tws[t] = sinf(a);
    }
    __syncthreads();

    if (blockIdx.x < 129) {
        const int e = t;
        if (e >= NE) return;
        const int u = e & 15, v = e >> 4;
        const float* src = (blockIdx.x == 128) ? b_aff
                                               : (W_aff + blockIdx.x * 256);
        float ar = 0.f, ai = 0.f;
        for (int rc = 0; rc < 256; ++rc) {
            int m = (u * (rc >> 4) + v * (rc & 15)) & 15;
            float x = src[rc];                      // uniform -> s_load
            ar = fmaf(x, twc[m], ar);
            ai = fmaf(x, -tws[m], ai);
        }
        if (blockIdx.x == 128) {
            bf[2 * e + 0] = ar;
            bf[2 * e + 1] = ai;
        } else {
            const int d = blockIdx.x;
            const int kt = d >> 5, kin = d & 31;
            const int lhi = (kin >> 3) * 16, i = kin & 7;
            const int c0 = 2 * e, c1 = 2 * e + 1;
            Bp[(((size_t)kt * NT + (c0 >> 4)) * 64 + lhi + (c0 & 15)) * 8 + i] =
                __float2half(ar);
            Bp[(((size_t)kt * NT + (c1 >> 4)) * 64 + lhi + (c1 & 15)) * 8 + i] =
                __float2half(ai);
        }
    } else {
        const int j = t;
        if (j >= 128) return;
        const int e = blockIdx.x - 129;            // 0..143
        const int u = e & 15, v = e >> 4;
        float A = 0.f, B = 0.f;
        for (int rc = 0; rc < 256; ++rc) {
            int m = (u * (rc >> 4) + v * (rc & 15)) & 15;
            float wv_ = W_mlp[rc * 128 + j];        // coalesced
            A = fmaf(wv_, twc[m], A);
            B = fmaf(wv_, tws[m], B);
        }
        const float s = ((v == 0) || (v == 8)) ? (1.0f / 256.0f)
                                               : (2.0f / 256.0f);
        W_eff2[e * 128 + j] = make_float2(A * s, -B * s);
    }
}

// ---------------------------------------------------------------------------
// Spectra GEMM via MFMA. 1250 blocks x 64 threads (1 wave = 16 nodes, no tail).
// A frag (16x32 f16): row = lane&15, k = kt*32 + (lane>>4)*8 + i (16B load).
// B frag: one coalesced 16B load from pre-packed Bp.
// D (f32x4): col = lane&15 (within nt tile), row = (lane>>4)*4 + r.
// ---------------------------------------------------------------------------
__global__ __launch_bounds__(64) void k_spectra_mfma(
    const __half* __restrict__ feat_h, const __half* __restrict__ Bp,
    const float* __restrict__ bf, __half* __restrict__ Fh)
{
    const int node0 = blockIdx.x * 16;
    const int lane  = threadIdx.x;
    const int row   = lane & 15, kg = lane >> 4;

    f16x8 a[4];
#pragma unroll
    for (int kt = 0; kt < 4; ++kt)
        a[kt] = *(const f16x8*)&feat_h[(node0 + row) * IN_DIM + kt * 32 + kg * 8];

#pragma unroll
    for (int nt = 0; nt < NT; ++nt) {
        f32x4 c = {0.f, 0.f, 0.f, 0.f};
#pragma unroll
        for (int kt = 0; kt < 4; ++kt) {
            const f16x8 b =
                *(const f16x8*)&Bp[(((size_t)kt * NT + nt) * 64 + lane) * 8];
            c = __builtin_amdgcn_mfma_f32_16x16x32_f16(a[kt], b, c, 0, 0, 0);
        }
        const int col = nt * 16 + row;
        const float bias = bf[col];
#pragma unroll
        for (int r = 0; r < 4; ++r) {
            const int nrow = kg * 4 + r;
            Fh[(size_t)(node0 + nrow) * NCOL + col] = __float2half(c[r] + bias);
        }
    }
}

// ---------------------------------------------------------------------------
// Gather + product + folded MLP (unchanged, proven 46 us). 8 nodes/block.
// ---------------------------------------------------------------------------
__global__ __launch_bounds__(256) void k_gather_mlp(
    const int* __restrict__ nbr, const __half2* __restrict__ F2h,
    const float2* __restrict__ W_eff2, const float* __restrict__ b_mlp,
    float* __restrict__ out)
{
    const int node0 = blockIdx.x * 8;
    const int tid  = threadIdx.x;
    const int lane = tid & 63;
    const int w    = __builtin_amdgcn_readfirstlane(tid >> 6);

    __shared__ float2 P_lds[8][NE];       // 9.2 KB
    __shared__ float  part[4][8][128];    // 16 KB

#pragma unroll
    for (int mi = 0; mi < 2; ++mi) {
        const int m = 2 * w + mi;
        const int* nrow = nbr + (node0 + m) * KNBR;

        __half2 fA[8], fB[8], fA2[8], fB2[8];
        const int eA = lane, eB = lane + 64;
#pragma unroll
        for (int k = 0; k < 8; ++k) {
            const __half2* base = F2h + (size_t)nrow[k] * NE;   // s_load idx
            fA[k] = base[eA];
            fB[k] = base[eB];
        }
#pragma unroll
        for (int k = 0; k < 8; ++k) {
            const __half2* base = F2h + (size_t)nrow[k + 8] * NE;
            fA2[k] = base[eA];
            fB2[k] = base[eB];
        }
        P_lds[m][eA] = cmul(cprod8h(fA), cprod8h(fA2));
        P_lds[m][eB] = cmul(cprod8h(fB), cprod8h(fB2));

        if (lane < 16) {
            const int eC = lane + 128;
            __half2 fC[8], fC2[8];
#pragma unroll
            for (int k = 0; k < 8; ++k) {
                fC[k]  = F2h[(size_t)nrow[k] * NE + eC];
                fC2[k] = F2h[(size_t)nrow[k + 8] * NE + eC];
            }
            P_lds[m][eC] = cmul(cprod8h(fC), cprod8h(fC2));
        }
    }
    __syncthreads();

    float acc0[8], acc1[8];
#pragma unroll
    for (int m = 0; m < 8; ++m) { acc0[m] = 0.f; acc1[m] = 0.f; }

    const int e0 = w * 36;
#pragma unroll 4
    for (int le = 0; le < 36; ++le) {
        const int e = e0 + le;                        // wave-uniform
        const float2 w0 = W_eff2[e * 128 + lane];
        const float2 w1 = W_eff2[e * 128 + 64 + lane];
#pragma unroll
        for (int m = 0; m < 8; ++m) {
            const float2 p = P_lds[m][e];             // uniform -> broadcast
            acc0[m] = fmaf(p.x, w0.x, fmaf(p.y, w0.y, acc0[m]));
            acc1[m] = fmaf(p.x, w1.x, fmaf(p.y, w1.y, acc1[m]));
        }
    }

#pragma unroll
    for (int m = 0; m < 8; ++m) {
        part[w][m][lane]      = acc0[m];
        part[w][m][lane + 64] = acc1[m];
    }
    __syncthreads();

    {
        const int m = tid >> 5;
        const int j = (tid & 31) * 4;
        float4 s = *(const float4*)&b_mlp[j];
#pragma unroll
        for (int w4 = 0; w4 < 4; ++w4) {
            const float4 p = *(const float4*)&part[w4][m][j];
            s.x += p.x; s.y += p.y; s.z += p.z; s.w += p.w;
        }
        *(float4*)&out[(node0 + m) * OUT_DIM + j] = s;
    }
}

extern "C" void kernel_launch(void* const* d_in, const int* in_sizes, int n_in,
                              void* d_out, int out_size, void* d_ws, size_t ws_size,
                              hipStream_t stream) {
    const float* feature   = (const float*)d_in[0];
    const int*   neighbors = (const int*)d_in[1];
    const float* W_aff     = (const float*)d_in[2];
    const float* b_aff     = (const float*)d_in[3];
    const float* W_mlp     = (const float*)d_in[4];
    const float* b_mlp     = (const float*)d_in[5];
    float*       out       = (float*)d_out;

    const int N = in_sizes[0] / IN_DIM;   // 20000

    // workspace layout
    __half*  Bp     = (__half*)d_ws;                    // 4*18*64*8 = 36864 halfs
    float*   bf     = (float*)(Bp + 36864);             // 288 f32
    float2*  W_eff2 = (float2*)(bf + 288);              // 144*128 float2
    __half*  feat_h = (__half*)(W_eff2 + NE * 128);     // N*128 halfs (5.1 MB)
    __half*  Fh     = feat_h + (size_t)N * IN_DIM;      // N*288 halfs (11.5 MB)

    k_feat_half<<<(N * IN_DIM) / 1024, 256, 0, stream>>>(
        feature, (__half2*)feat_h);
    k_prep<<<273, 256, 0, stream>>>(W_aff, b_aff, W_mlp, Bp, bf, W_eff2);
    k_spectra_mfma<<<N / 16, 64, 0, stream>>>(feat_h, Bp, bf, Fh);
    k_gather_mlp<<<N / 8, 256, 0, stream>>>(
        neighbors, (const __half2*)Fh, W_eff2, b_mlp, out);
}

// Round 8
// 71.426 us; speedup vs baseline: 1.7390x; 1.2130x over previous
//
#include <hip/hip_runtime.h>
#include <hip/hip_fp16.h>
#include <math.h>

// N=20000, K=16, in_dim=128, out_dim=128, H1=H2=16
// Hermitian-reduced spectrum: e = v*16 + u, v=0..8, u=0..15  -> NE=144
// Spectra GEMM (MFMA fp16): C[20000 x 288] = feat_h @ B, B packed frag-order.
// MLP GEMM (MFMA bf16):     out[16 x 128] = P_bf16[16 x 288] @ Wp + b_mlp,
//   per 16-node block; k-index = 2e + {0:re, 1:im}; kt = v (9 tiles of 32).
#define IN_DIM 128
#define NE 144
#define NCOL 288           // NE*2 half-columns
#define NT 18              // NCOL/16 N-tiles (spectra GEMM)
#define OUT_DIM 128
#define KNBR 16

typedef _Float16 f16x8 __attribute__((ext_vector_type(8)));
typedef short    bf16x8 __attribute__((ext_vector_type(8)));
typedef float    f32x4 __attribute__((ext_vector_type(4)));

__device__ __forceinline__ float2 cmul(float2 a, float2 b) {
    return make_float2(a.x * b.x - a.y * b.y, a.x * b.y + a.y * b.x);
}

__device__ __forceinline__ float2 cprod16h(const __half2* f) {
    float2 c[16];
#pragma unroll
    for (int k = 0; k < 16; ++k) c[k] = __half22float2(f[k]);
    float2 g[8];
#pragma unroll
    for (int k = 0; k < 8; ++k) g[k] = cmul(c[2 * k], c[2 * k + 1]);
#pragma unroll
    for (int k = 0; k < 4; ++k) g[k] = cmul(g[2 * k], g[2 * k + 1]);
    return cmul(cmul(g[0], g[1]), cmul(g[2], g[3]));
}

__device__ __forceinline__ unsigned short f2bf(float x) {
    unsigned int u = __float_as_uint(x);
    unsigned int r = (u + 0x7FFFu + ((u >> 16) & 1u)) >> 16;
    return (unsigned short)r;
}

// ---------------------------------------------------------------------------
// feat f32 -> f16, fully coalesced.
// ---------------------------------------------------------------------------
__global__ __launch_bounds__(256) void k_feat_half(
    const float* __restrict__ feat, __half2* __restrict__ feat_h2)
{
    const int idx = blockIdx.x * 256 + threadIdx.x;
    const float4 v = ((const float4*)feat)[idx];
    feat_h2[2 * idx + 0] = __floats2half2_rn(v.x, v.y);
    feat_h2[2 * idx + 1] = __floats2half2_rn(v.z, v.w);
}

// ---------------------------------------------------------------------------
// Merged prep.
// Blocks 0..127 (row d): forward-DFT fold of W_aff -> Bp (fp16 frag order).
// Block 128: bias -> bf[288] f32.
// Blocks 129..272 (e=blk-129): IFFT2+Re+Hermitian fold of W_mlp -> Wp
//   (bf16, MFMA-B fragment order: kt=v, k32=2u+{0,1}).
// ---------------------------------------------------------------------------
__global__ __launch_bounds__(256) void k_prep(
    const float* __restrict__ W_aff, const float* __restrict__ b_aff,
    const float* __restrict__ W_mlp,
    __half* __restrict__ Bp, float* __restrict__ bf,
    unsigned short* __restrict__ Wp)
{
    __shared__ float twc[16], tws[16];
    const int t = threadIdx.x;
    if (t < 16) {
        float a = (float)M_PI * (float)t / 8.0f;   // 2*pi*t/16
        twc[t] = cosf(a);
        tws[t] = sinf(a);
    }
    __syncthreads();

    if (blockIdx.x < 129) {
        const int e = t;
        if (e >= NE) return;
        const int u = e & 15, v = e >> 4;
        const float* src = (blockIdx.x == 128) ? b_aff
                                               : (W_aff + blockIdx.x * 256);
        float ar = 0.f, ai = 0.f;
        for (int rc = 0; rc < 256; ++rc) {
            int m = (u * (rc >> 4) + v * (rc & 15)) & 15;
            float x = src[rc];                      // uniform -> s_load
            ar = fmaf(x, twc[m], ar);
            ai = fmaf(x, -tws[m], ai);
        }
        if (blockIdx.x == 128) {
            bf[2 * e + 0] = ar;
            bf[2 * e + 1] = ai;
        } else {
            const int d = blockIdx.x;
            const int kt = d >> 5, kin = d & 31;
            const int lhi = (kin >> 3) * 16, i = kin & 7;
            const int c0 = 2 * e, c1 = 2 * e + 1;
            Bp[(((size_t)kt * NT + (c0 >> 4)) * 64 + lhi + (c0 & 15)) * 8 + i] =
                __float2half(ar);
            Bp[(((size_t)kt * NT + (c1 >> 4)) * 64 + lhi + (c1 & 15)) * 8 + i] =
                __float2half(ai);
        }
    } else {
        const int j = t;
        if (j >= 128) return;
        const int e = blockIdx.x - 129;            // 0..143
        const int u = e & 15, v = e >> 4;
        float A = 0.f, B = 0.f;
        for (int rc = 0; rc < 256; ++rc) {
            int m = (u * (rc >> 4) + v * (rc & 15)) & 15;
            float wv_ = W_mlp[rc * 128 + j];        // coalesced
            A = fmaf(wv_, twc[m], A);
            B = fmaf(wv_, tws[m], B);
        }
        const float s = ((v == 0) || (v == 8)) ? (1.0f / 256.0f)
                                               : (2.0f / 256.0f);
        // B-frag slot: kt=v, ntg=j>>4, kgrp=u>>2, col=j&15, i=2*(u&3)+{0,1}
        const size_t base =
            (((size_t)v * 8 + (j >> 4)) * 64 + (u >> 2) * 16 + (j & 15)) * 8 +
            2 * (u & 3);
        Wp[base + 0] = f2bf(A * s);
        Wp[base + 1] = f2bf(-B * s);
    }
}

// ---------------------------------------------------------------------------
// Spectra GEMM via MFMA (unchanged). 1250 blocks x 64 threads, 16 nodes each.
// ---------------------------------------------------------------------------
__global__ __launch_bounds__(64) void k_spectra_mfma(
    const __half* __restrict__ feat_h, const __half* __restrict__ Bp,
    const float* __restrict__ bf, __half* __restrict__ Fh)
{
    const int node0 = blockIdx.x * 16;
    const int lane  = threadIdx.x;
    const int row   = lane & 15, kg = lane >> 4;

    f16x8 a[4];
#pragma unroll
    for (int kt = 0; kt < 4; ++kt)
        a[kt] = *(const f16x8*)&feat_h[(node0 + row) * IN_DIM + kt * 32 + kg * 8];

#pragma unroll
    for (int nt = 0; nt < NT; ++nt) {
        f32x4 c = {0.f, 0.f, 0.f, 0.f};
#pragma unroll
        for (int kt = 0; kt < 4; ++kt) {
            const f16x8 b =
                *(const f16x8*)&Bp[(((size_t)kt * NT + nt) * 64 + lane) * 8];
            c = __builtin_amdgcn_mfma_f32_16x16x32_f16(a[kt], b, c, 0, 0, 0);
        }
        const int col = nt * 16 + row;
        const float bias = bf[col];
#pragma unroll
        for (int r = 0; r < 4; ++r) {
            const int nrow = kg * 4 + r;
            Fh[(size_t)(node0 + nrow) * NCOL + col] = __float2half(c[r] + bias);
        }
    }
}

// ---------------------------------------------------------------------------
// Gather + product + MFMA MLP. 16 nodes/block, 256 threads (4 waves).
// Product: wave w owns nodes 4w..4w+3; lane covers e = lane, lane+64,
//   lane+128 (<16). P (fp32) -> bf16 -> LDS in MFMA-A fragment layout
//   A_lds[kt=v][kgrp][node][8], padded 8 halfs per 128 -> <=2-way conflicts.
// MLP: wave w owns cols [32w, 32w+32): 9 kt x 2 nt mfma_f32_16x16x32_bf16;
//   B from pre-packed Wp (coalesced 16B); epilogue adds b_mlp.
// ---------------------------------------------------------------------------
__global__ __launch_bounds__(256) void k_gather_mlp(
    const int* __restrict__ nbr, const __half2* __restrict__ F2h,
    const unsigned short* __restrict__ Wp, const float* __restrict__ b_mlp,
    float* __restrict__ out)
{
    const int node0 = blockIdx.x * 16;
    const int tid  = threadIdx.x;
    const int lane = tid & 63;
    const int w    = __builtin_amdgcn_readfirstlane(tid >> 6);

    __shared__ unsigned short A_lds[9 * 4 * 136];   // 9.8 KB, pad 8/128

    // ---- product phase: 4 nodes per wave
#pragma unroll
    for (int m = 0; m < 4; ++m) {
        const int gm = w * 4 + m;                     // block-local node 0..15
        const int* nrow = nbr + (node0 + gm) * KNBR;  // uniform -> s_load

        __half2 f[KNBR];
        // e = lane
#pragma unroll
        for (int k = 0; k < KNBR; ++k) f[k] = F2h[nrow[k] * NE + lane];
        {
            const float2 p = cprod16h(f);
            const int u = lane & 15, v = lane >> 4;
            const int off = ((v * 4 + (u >> 2)) * 136) + gm * 8 + 2 * (u & 3);
            *(ushort2*)&A_lds[off] = make_ushort2(f2bf(p.x), f2bf(p.y));
        }
        // e = 64 + lane
#pragma unroll
        for (int k = 0; k < KNBR; ++k) f[k] = F2h[nrow[k] * NE + 64 + lane];
        {
            const float2 p = cprod16h(f);
            const int u = lane & 15, v = 4 + (lane >> 4);
            const int off = ((v * 4 + (u >> 2)) * 136) + gm * 8 + 2 * (u & 3);
            *(ushort2*)&A_lds[off] = make_ushort2(f2bf(p.x), f2bf(p.y));
        }
        // e = 128 + lane (lane < 16)
        if (lane < 16) {
#pragma unroll
            for (int k = 0; k < KNBR; ++k) f[k] = F2h[nrow[k] * NE + 128 + lane];
            const float2 p = cprod16h(f);
            const int u = lane;
            const int off = ((8 * 4 + (u >> 2)) * 136) + gm * 8 + 2 * (u & 3);
            *(ushort2*)&A_lds[off] = make_ushort2(f2bf(p.x), f2bf(p.y));
        }
    }
    __syncthreads();

    // ---- MFMA MLP: wave w -> cols [32w, 32w+32)
    f32x4 c0 = {0.f, 0.f, 0.f, 0.f}, c1 = {0.f, 0.f, 0.f, 0.f};
#pragma unroll
    for (int kt = 0; kt < 9; ++kt) {
        const bf16x8 a =
            *(const bf16x8*)&A_lds[(kt * 4 + (lane >> 4)) * 136 + (lane & 15) * 8];
        const bf16x8 b0 = *(const bf16x8*)
            &Wp[(((size_t)kt * 8 + (w * 2 + 0)) * 64 + lane) * 8];
        const bf16x8 b1 = *(const bf16x8*)
            &Wp[(((size_t)kt * 8 + (w * 2 + 1)) * 64 + lane) * 8];
        c0 = __builtin_amdgcn_mfma_f32_16x16x32_bf16(a, b0, c0, 0, 0, 0);
        c1 = __builtin_amdgcn_mfma_f32_16x16x32_bf16(a, b1, c1, 0, 0, 0);
    }

    // ---- epilogue: + bias, store (rows = nodes, coalesced 64B per quarter)
    {
        const int col0 = (w * 2 + 0) * 16 + (lane & 15);
        const int col1 = (w * 2 + 1) * 16 + (lane & 15);
        const float bias0 = b_mlp[col0];
        const float bias1 = b_mlp[col1];
#pragma unroll
        for (int r = 0; r < 4; ++r) {
            const int row = (lane >> 4) * 4 + r;
            out[(node0 + row) * OUT_DIM + col0] = c0[r] + bias0;
            out[(node0 + row) * OUT_DIM + col1] = c1[r] + bias1;
        }
    }
}

extern "C" void kernel_launch(void* const* d_in, const int* in_sizes, int n_in,
                              void* d_out, int out_size, void* d_ws, size_t ws_size,
                              hipStream_t stream) {
    const float* feature   = (const float*)d_in[0];
    const int*   neighbors = (const int*)d_in[1];
    const float* W_aff     = (const float*)d_in[2];
    const float* b_aff     = (const float*)d_in[3];
    const float* W_mlp     = (const float*)d_in[4];
    const float* b_mlp     = (const float*)d_in[5];
    float*       out       = (float*)d_out;

    const int N = in_sizes[0] / IN_DIM;   // 20000

    // workspace layout
    __half*         Bp     = (__half*)d_ws;               // 36864 halfs
    float*          bf     = (float*)(Bp + 36864);        // 288 f32
    unsigned short* Wp     = (unsigned short*)(bf + 288); // 36864 bf16
    __half*         feat_h = (__half*)(Wp + 36864);       // N*128 (5.1 MB)
    __half*         Fh     = feat_h + (size_t)N * IN_DIM; // N*288 (11.5 MB)

    k_feat_half<<<(N * IN_DIM) / 1024, 256, 0, stream>>>(
        feature, (__half2*)feat_h);
    k_prep<<<273, 256, 0, stream>>>(W_aff, b_aff, W_mlp, Bp, bf, Wp);
    k_spectra_mfma<<<N / 16, 64, 0, stream>>>(feat_h, Bp, bf, Fh);
    k_gather_mlp<<<N / 16, 256, 0, stream>>>(
        neighbors, (const __half2*)Fh, Wp, b_mlp, out);
}

// Round 9
// 51.795 us; speedup vs baseline: 2.3981x; 1.3790x over previous
//
#include <hip/hip_runtime.h>
#include <hip/hip_fp16.h>
#include <math.h>

// N=20000, K=16, in_dim=128, out_dim=128, H1=H2=16
// Hermitian-reduced spectrum: e = v*16 + u, v=0..8, u=0..15  -> NE=144
// Spectra GEMM (MFMA fp16): C[20000 x 288] = feat(f16) @ B, B packed frag-order.
// MLP GEMM (MFMA bf16):     out[16 x 128] = P_bf16[16 x 288] @ Wp + b_mlp.
#define IN_DIM 128
#define NE 144
#define NCOL 288           // NE*2 half-columns
#define NT 18              // NCOL/16 N-tiles (spectra GEMM)
#define OUT_DIM 128
#define KNBR 16

typedef _Float16 f16x8 __attribute__((ext_vector_type(8)));
typedef short    bf16x8 __attribute__((ext_vector_type(8)));
typedef float    f32x4 __attribute__((ext_vector_type(4)));

__device__ __forceinline__ float2 cmul(float2 a, float2 b) {
    return make_float2(a.x * b.x - a.y * b.y, a.x * b.y + a.y * b.x);
}

__device__ __forceinline__ float2 h2f(unsigned int u) {
    return __half22float2(__builtin_bit_cast(__half2, u));
}

__device__ __forceinline__ unsigned int u4c(const uint4& v, int j) {
    return j == 0 ? v.x : j == 1 ? v.y : j == 2 ? v.z : v.w;
}

__device__ __forceinline__ unsigned short f2bf(float x) {
    unsigned int u = __float_as_uint(x);
    unsigned int r = (u + 0x7FFFu + ((u >> 16) & 1u)) >> 16;
    return (unsigned short)r;
}

// ---------------------------------------------------------------------------
// Merged prep (unchanged from R8).
// Blocks 0..127 (row d): forward-DFT fold of W_aff -> Bp (fp16 frag order).
// Block 128: bias -> bf[288] f32.
// Blocks 129..272 (e=blk-129): IFFT2+Re+Hermitian fold of W_mlp -> Wp (bf16).
// ---------------------------------------------------------------------------
__global__ __launch_bounds__(256) void k_prep(
    const float* __restrict__ W_aff, const float* __restrict__ b_aff,
    const float* __restrict__ W_mlp,
    __half* __restrict__ Bp, float* __restrict__ bf,
    unsigned short* __restrict__ Wp)
{
    __shared__ float twc[16], tws[16];
    const int t = threadIdx.x;
    if (t < 16) {
        float a = (float)M_PI * (float)t / 8.0f;   // 2*pi*t/16
        twc[t] = cosf(a);
        tws[t] = sinf(a);
    }
    __syncthreads();

    if (blockIdx.x < 129) {
        const int e = t;
        if (e >= NE) return;
        const int u = e & 15, v = e >> 4;
        const float* src = (blockIdx.x == 128) ? b_aff
                                               : (W_aff + blockIdx.x * 256);
        float ar = 0.f, ai = 0.f;
        for (int rc = 0; rc < 256; ++rc) {
            int m = (u * (rc >> 4) + v * (rc & 15)) & 15;
            float x = src[rc];                      // uniform -> s_load
            ar = fmaf(x, twc[m], ar);
            ai = fmaf(x, -tws[m], ai);
        }
        if (blockIdx.x == 128) {
            bf[2 * e + 0] = ar;
            bf[2 * e + 1] = ai;
        } else {
            const int d = blockIdx.x;
            const int kt = d >> 5, kin = d & 31;
            const int lhi = (kin >> 3) * 16, i = kin & 7;
            const int c0 = 2 * e, c1 = 2 * e + 1;
            Bp[(((size_t)kt * NT + (c0 >> 4)) * 64 + lhi + (c0 & 15)) * 8 + i] =
                __float2half(ar);
            Bp[(((size_t)kt * NT + (c1 >> 4)) * 64 + lhi + (c1 & 15)) * 8 + i] =
                __float2half(ai);
        }
    } else {
        const int j = t;
        if (j >= 128) return;
        const int e = blockIdx.x - 129;            // 0..143
        const int u = e & 15, v = e >> 4;
        float A = 0.f, B = 0.f;
        for (int rc = 0; rc < 256; ++rc) {
            int m = (u * (rc >> 4) + v * (rc & 15)) & 15;
            float wv_ = W_mlp[rc * 128 + j];        // coalesced
            A = fmaf(wv_, twc[m], A);
            B = fmaf(wv_, tws[m], B);
        }
        const float s = ((v == 0) || (v == 8)) ? (1.0f / 256.0f)
                                               : (2.0f / 256.0f);
        const size_t base =
            (((size_t)v * 8 + (j >> 4)) * 64 + (u >> 2) * 16 + (j & 15)) * 8 +
            2 * (u & 3);
        Wp[base + 0] = f2bf(A * s);
        Wp[base + 1] = f2bf(-B * s);
    }
}

// ---------------------------------------------------------------------------
// Spectra GEMM v2: fused f32->f16 A-load, 3-way nt-split for occupancy.
// Grid 3750 x 64 threads. Block b: nodes (b/3)*16..+16, nt range (b%3)*6..+6.
// ---------------------------------------------------------------------------
__global__ __launch_bounds__(64) void k_spectra_mfma(
    const float* __restrict__ feat, const __half* __restrict__ Bp,
    const float* __restrict__ bf, __half* __restrict__ Fh)
{
    const int node0 = (blockIdx.x / 3) * 16;
    const int ntb   = (blockIdx.x % 3) * 6;
    const int lane  = threadIdx.x;
    const int row   = lane & 15, kg = lane >> 4;

    f16x8 a[4];
#pragma unroll
    for (int kt = 0; kt < 4; ++kt) {
        const float* p = &feat[(node0 + row) * IN_DIM + kt * 32 + kg * 8];
        const float4 fa = *(const float4*)p;
        const float4 fb = *(const float4*)(p + 4);
        f16x8 t = {(_Float16)fa.x, (_Float16)fa.y, (_Float16)fa.z,
                   (_Float16)fa.w, (_Float16)fb.x, (_Float16)fb.y,
                   (_Float16)fb.z, (_Float16)fb.w};
        a[kt] = t;
    }

#pragma unroll
    for (int t = 0; t < 6; ++t) {
        const int nt = ntb + t;
        f32x4 c = {0.f, 0.f, 0.f, 0.f};
#pragma unroll
        for (int kt = 0; kt < 4; ++kt) {
            const f16x8 b =
                *(const f16x8*)&Bp[(((size_t)kt * NT + nt) * 64 + lane) * 8];
            c = __builtin_amdgcn_mfma_f32_16x16x32_f16(a[kt], b, c, 0, 0, 0);
        }
        const int col = nt * 16 + row;
        const float bias = bf[col];
#pragma unroll
        for (int r = 0; r < 4; ++r) {
            const int nrow = kg * 4 + r;
            Fh[(size_t)(node0 + nrow) * NCOL + col] = __float2half(c[r] + bias);
        }
    }
}

// ---------------------------------------------------------------------------
// Gather + product + MFMA MLP v2. 16 nodes/block, 256 threads (4 waves).
// Product: wave w owns nodes 4w..4w+3. Lane (<36) loads 16B = 4 complex
//   elements e = 4*lane..4*lane+3 per neighbor -> 16 loads/node (was 48).
//   Product tree identical to R8 (bit-identical result). P -> bf16 -> LDS
//   in MFMA-A fragment layout (padded).
// MLP: wave w owns cols [32w, 32w+32): 9 kt x 2 nt mfma_f32_16x16x32_bf16.
// ---------------------------------------------------------------------------
__global__ __launch_bounds__(256) void k_gather_mlp(
    const int* __restrict__ nbr, const __half* __restrict__ Fh,
    const unsigned short* __restrict__ Wp, const float* __restrict__ b_mlp,
    float* __restrict__ out)
{
    const int node0 = blockIdx.x * 16;
    const int tid  = threadIdx.x;
    const int lane = tid & 63;
    const int w    = __builtin_amdgcn_readfirstlane(tid >> 6);

    __shared__ unsigned short A_lds[9 * 4 * 136];   // 9.8 KB

    // ---- product phase: 4 nodes per wave, lanes 0..35 active
#pragma unroll
    for (int m = 0; m < 4; ++m) {
        const int gm = w * 4 + m;                     // block-local node 0..15
        const int* nrow = nbr + (node0 + gm) * KNBR;  // uniform -> s_load

        if (lane < 36) {
            uint4 f[8];
#pragma unroll
            for (int k = 0; k < 8; ++k)
                f[k] = *(const uint4*)&Fh[(size_t)nrow[k] * NCOL + lane * 8];
            float2 q0[4];
#pragma unroll
            for (int j = 0; j < 4; ++j) {
                float2 c[8];
#pragma unroll
                for (int k = 0; k < 8; ++k) c[k] = h2f(u4c(f[k], j));
                const float2 g0 = cmul(c[0], c[1]), g1 = cmul(c[2], c[3]);
                const float2 g2 = cmul(c[4], c[5]), g3 = cmul(c[6], c[7]);
                q0[j] = cmul(cmul(g0, g1), cmul(g2, g3));
            }
#pragma unroll
            for (int k = 0; k < 8; ++k)
                f[k] = *(const uint4*)&Fh[(size_t)nrow[k + 8] * NCOL + lane * 8];
#pragma unroll
            for (int j = 0; j < 4; ++j) {
                float2 c[8];
#pragma unroll
                for (int k = 0; k < 8; ++k) c[k] = h2f(u4c(f[k], j));
                const float2 g0 = cmul(c[0], c[1]), g1 = cmul(c[2], c[3]);
                const float2 g2 = cmul(c[4], c[5]), g3 = cmul(c[6], c[7]);
                const float2 q1 = cmul(cmul(g0, g1), cmul(g2, g3));
                const float2 p = cmul(q0[j], q1);

                const int e = lane * 4 + j;           // 0..143
                const int u = e & 15, v = e >> 4;
                const int off =
                    ((v * 4 + (u >> 2)) * 136) + gm * 8 + 2 * (u & 3);
                *(ushort2*)&A_lds[off] = make_ushort2(f2bf(p.x), f2bf(p.y));
            }
        }
    }
    __syncthreads();

    // ---- MFMA MLP: wave w -> cols [32w, 32w+32)
    f32x4 c0 = {0.f, 0.f, 0.f, 0.f}, c1 = {0.f, 0.f, 0.f, 0.f};
#pragma unroll
    for (int kt = 0; kt < 9; ++kt) {
        const bf16x8 a =
            *(const bf16x8*)&A_lds[(kt * 4 + (lane >> 4)) * 136 + (lane & 15) * 8];
        const bf16x8 b0 = *(const bf16x8*)
            &Wp[(((size_t)kt * 8 + (w * 2 + 0)) * 64 + lane) * 8];
        const bf16x8 b1 = *(const bf16x8*)
            &Wp[(((size_t)kt * 8 + (w * 2 + 1)) * 64 + lane) * 8];
        c0 = __builtin_amdgcn_mfma_f32_16x16x32_bf16(a, b0, c0, 0, 0, 0);
        c1 = __builtin_amdgcn_mfma_f32_16x16x32_bf16(a, b1, c1, 0, 0, 0);
    }

    // ---- epilogue: + bias, store
    {
        const int col0 = (w * 2 + 0) * 16 + (lane & 15);
        const int col1 = (w * 2 + 1) * 16 + (lane & 15);
        const float bias0 = b_mlp[col0];
        const float bias1 = b_mlp[col1];
#pragma unroll
        for (int r = 0; r < 4; ++r) {
            const int row = (lane >> 4) * 4 + r;
            out[(node0 + row) * OUT_DIM + col0] = c0[r] + bias0;
            out[(node0 + row) * OUT_DIM + col1] = c1[r] + bias1;
        }
    }
}

extern "C" void kernel_launch(void* const* d_in, const int* in_sizes, int n_in,
                              void* d_out, int out_size, void* d_ws, size_t ws_size,
                              hipStream_t stream) {
    const float* feature   = (const float*)d_in[0];
    const int*   neighbors = (const int*)d_in[1];
    const float* W_aff     = (const float*)d_in[2];
    const float* b_aff     = (const float*)d_in[3];
    const float* W_mlp     = (const float*)d_in[4];
    const float* b_mlp     = (const float*)d_in[5];
    float*       out       = (float*)d_out;

    const int N = in_sizes[0] / IN_DIM;   // 20000

    // workspace layout
    __half*         Bp = (__half*)d_ws;                   // 36864 halfs
    float*          bf = (float*)(Bp + 36864);            // 288 f32
    unsigned short* Wp = (unsigned short*)(bf + 288);     // 36864 bf16
    __half*         Fh = (__half*)(Wp + 36864);           // N*288 (11.5 MB)

    k_prep<<<273, 256, 0, stream>>>(W_aff, b_aff, W_mlp, Bp, bf, Wp);
    k_spectra_mfma<<<3750, 64, 0, stream>>>(feature, Bp, bf, Fh);
    k_gather_mlp<<<N / 16, 256, 0, stream>>>(neighbors, Fh, Wp, b_mlp, out);
}